// Round 2
// baseline (301.490 us; speedup 1.0000x reference)
//
#include <hip/hip_runtime.h>
#include <hip/hip_bf16.h>

// B=4, S=2048, D=1024 causal attention head, f32 in/out, bf16 MFMA compute.
//
// ws layout (bytes):
//   [0,16MB)    xb    bf16 [8192][1024]
//   [16,22MB)   Wb    bf16 [3072][1024]   (Wq;Wk;Wv stacked, B^T layout)
//   [22,23MB)   biasb f32  [3072]
//   [23,55MB)   QK    bf16 [8192][2048]   (cols 0:1024=Q, 1024:2048=K)
//   [55,71MB)   Vt    bf16 [4][1024][2048]  (written directly by projection epilogue)
//   [71,135MB)  S     f32  [4][2048][2048]; P bf16 overlaid in-place (row pitch 4096 ushorts)

typedef __attribute__((ext_vector_type(8))) short short8;
typedef __attribute__((ext_vector_type(4))) float f32x4;
typedef __attribute__((ext_vector_type(4))) unsigned short ushort4v;

static __device__ __forceinline__ unsigned short f2b(float f) {
  union { __hip_bfloat16 h; unsigned short u; } cv;
  cv.h = __float2bfloat16(f);
  return cv.u;
}

#define GLOAD_LDS16(gsrc, ldst)                                              \
  __builtin_amdgcn_global_load_lds(                                          \
      (const __attribute__((address_space(1))) void*)(gsrc),                 \
      (__attribute__((address_space(3))) void*)(ldst), 16, 0, 0)

// ---------------- conversions ----------------
__global__ __launch_bounds__(256) void cvt4(const float* __restrict__ in,
                                            unsigned short* __restrict__ out, int n4) {
  int i = blockIdx.x * blockDim.x + threadIdx.x;
  if (i >= n4) return;
  float4 v = reinterpret_cast<const float4*>(in)[i];
  ushort4v o;
  o.x = f2b(v.x); o.y = f2b(v.y); o.z = f2b(v.z); o.w = f2b(v.w);
  reinterpret_cast<ushort4v*>(out)[i] = o;
}

// W cvt (3 matrices) + bias concat in one launch. grid = 3072 + 12.
__global__ __launch_bounds__(256) void prep_w(
    const float* __restrict__ Wq, const float* __restrict__ Wk, const float* __restrict__ Wv,
    const float* __restrict__ bq, const float* __restrict__ bk, const float* __restrict__ bv,
    unsigned short* __restrict__ Wb, float* __restrict__ biasb) {
  int id = blockIdx.x;
  if (id < 3072) {
    int sel = id >> 10;
    const float* src = sel == 0 ? Wq : sel == 1 ? Wk : Wv;
    int i = (id & 1023) * 256 + threadIdx.x;  // float4 index, < 262144
    float4 v = reinterpret_cast<const float4*>(src)[i];
    ushort4v o;
    o.x = f2b(v.x); o.y = f2b(v.y); o.z = f2b(v.z); o.w = f2b(v.w);
    reinterpret_cast<ushort4v*>(Wb + (long)sel * 1048576)[i] = o;
  } else {
    int i = (id - 3072) * 256 + threadIdx.x;  // 0..3071
    if (i < 3072) {
      int sel = i >> 10;
      const float* src = sel == 0 ? bq : sel == 1 ? bk : bv;
      biasb[i] = src[i & 1023];
    }
  }
}

// ---------------- GEMM: C[M][N] = A[M][K] * B[N][K]^T ----------------
// 128x128 tile, BK=64, 4 waves (2x2). LDS XOR-swizzle on pre-swizzled global src.
// MODE 0: projection. bx<16 -> QK bf16 (+bias, ldc=2048); bx>=16 -> Vt transposed write.
// MODE 1: f32 out * scale, skip bx>by (scores).
template <int MODE>
__global__ __launch_bounds__(256, 4) void gemm128(
    const unsigned short* __restrict__ A, const unsigned short* __restrict__ B,
    void* __restrict__ Cout, const float* __restrict__ bias,
    unsigned short* __restrict__ VtOut, float scale,
    int lda, int ldb, int ldc, int ktiles,
    long aStride, long bStride, long cStride) {
  int bx = blockIdx.x, by = blockIdx.y, bz = blockIdx.z;
  if (MODE == 1 && bx > by) return;

  __shared__ unsigned short sA[128 * 64];
  __shared__ unsigned short sB[128 * 64];

  int tid = threadIdx.x;
  int lane = tid & 63;
  int w = tid >> 6;
  int wr = w >> 1, wc = w & 1;

  const unsigned short* Ab = A + bz * aStride + (long)by * 128 * lda;
  const unsigned short* Bb = B + bz * bStride + (long)bx * 128 * ldb;

  f32x4 acc[4][4];
#pragma unroll
  for (int m = 0; m < 4; ++m)
#pragma unroll
    for (int n = 0; n < 4; ++n) acc[m][n] = (f32x4){0.f, 0.f, 0.f, 0.f};

  for (int kt = 0; kt < ktiles; ++kt) {
    __syncthreads();
#pragma unroll
    for (int c = 0; c < 8; ++c) {
      int chunk = w * 8 + c;
      int half = chunk & 15;
      int L = half * 1024 + lane * 16;
      int row = L >> 7;
      int gs = ((L >> 4) & 7) ^ (row & 7);
      if (chunk < 16) {
        GLOAD_LDS16(Ab + (long)row * lda + kt * 64 + gs * 8, sA + half * 512);
      } else {
        GLOAD_LDS16(Bb + (long)row * ldb + kt * 64 + gs * 8, sB + half * 512);
      }
    }
    __syncthreads();

#pragma unroll
    for (int kk = 0; kk < 2; ++kk) {
      short8 af[4], bfr[4];
#pragma unroll
      for (int m = 0; m < 4; ++m) {
        int row = wr * 64 + m * 16 + (lane & 15);
        int g = kk * 4 + (lane >> 4);
        af[m] = *(const short8*)((const char*)sA + row * 128 + ((g ^ (row & 7)) << 4));
      }
#pragma unroll
      for (int n = 0; n < 4; ++n) {
        int row = wc * 64 + n * 16 + (lane & 15);
        int g = kk * 4 + (lane >> 4);
        bfr[n] = *(const short8*)((const char*)sB + row * 128 + ((g ^ (row & 7)) << 4));
      }
#pragma unroll
      for (int m = 0; m < 4; ++m)
#pragma unroll
        for (int n = 0; n < 4; ++n)
          acc[m][n] = __builtin_amdgcn_mfma_f32_16x16x32_bf16(af[m], bfr[n], acc[m][n], 0, 0, 0);
    }
  }

  // C/D layout: col = lane&15, row = (lane>>4)*4 + reg
  int r0 = by * 128 + wr * 64 + (lane >> 4) * 4;
  int c0 = bx * 128 + wc * 64 + (lane & 15);
  if (MODE == 0) {
    if (bx < 16) {
      unsigned short* C = (unsigned short*)Cout;
#pragma unroll
      for (int m = 0; m < 4; ++m)
#pragma unroll
        for (int n = 0; n < 4; ++n) {
          int gc = c0 + n * 16;
          float bv = bias[gc];
#pragma unroll
          for (int r = 0; r < 4; ++r)
            C[(long)(r0 + m * 16 + r) * ldc + gc] = f2b(acc[m][n][r] + bv);
        }
    } else {
      // transposed V write: Vt[b][d][s]
      long b = by >> 4;
      int s0 = (by & 15) * 128 + wr * 64 + (lane >> 4) * 4;
      int d0 = (bx - 16) * 128 + wc * 64 + (lane & 15);
      unsigned short* VT = VtOut + b * (1024L * 2048);
#pragma unroll
      for (int m = 0; m < 4; ++m)
#pragma unroll
        for (int n = 0; n < 4; ++n) {
          int d = d0 + n * 16;
          float bv = bias[2048 + d];
          ushort4v o;
          o.x = f2b(acc[m][n][0] + bv);
          o.y = f2b(acc[m][n][1] + bv);
          o.z = f2b(acc[m][n][2] + bv);
          o.w = f2b(acc[m][n][3] + bv);
          *(ushort4v*)(VT + (long)d * 2048 + s0 + m * 16) = o;
        }
    }
  } else {
    float* C = (float*)Cout + bz * cStride;
#pragma unroll
    for (int m = 0; m < 4; ++m)
#pragma unroll
      for (int n = 0; n < 4; ++n)
#pragma unroll
        for (int r = 0; r < 4; ++r)
          C[(long)(r0 + m * 16 + r) * ldc + c0 + n * 16] = acc[m][n][r] * scale;
  }
}

// ---------------- PV: out[b] = P[b] * Vt[b]^T, pair-balanced causal ----------------
// grid (8,8,4) x 512 thr. Block handles strips {15-byp, byp}: constant 34 ktiles.
__global__ __launch_bounds__(512, 2) void pv_gemm(
    const unsigned short* __restrict__ P, const unsigned short* __restrict__ Vt,
    float* __restrict__ out) {
  __shared__ unsigned short sA[128 * 64];
  __shared__ unsigned short sB[128 * 64];
  int tid = threadIdx.x;
  int lane = tid & 63;
  int w = tid >> 6;           // 0..7
  int wr = w >> 2, wc = w & 3;
  int bx = blockIdx.x, byp = blockIdx.y, bz = blockIdx.z;
  const unsigned short* Pb = P + bz * (2048L * 4096);
  const unsigned short* Bb = Vt + bz * (1024L * 2048) + (long)bx * 128 * 2048;
  float* Ob = out + bz * (2048L * 1024);

#pragma unroll
  for (int half = 0; half < 2; ++half) {
    int strip = half == 0 ? (15 - byp) : byp;
    int nkt = (strip + 1) * 2;
    const unsigned short* Ab = Pb + (long)strip * 128 * 4096;

    f32x4 acc[4][2];
#pragma unroll
    for (int m = 0; m < 4; ++m)
#pragma unroll
      for (int n = 0; n < 2; ++n) acc[m][n] = (f32x4){0.f, 0.f, 0.f, 0.f};

    for (int kt = 0; kt < nkt; ++kt) {
      __syncthreads();
#pragma unroll
      for (int c = 0; c < 4; ++c) {
        int chunk = w * 4 + c;
        int hh = chunk & 15;
        int L = hh * 1024 + lane * 16;
        int row = L >> 7;
        int gs = ((L >> 4) & 7) ^ (row & 7);
        if (chunk < 16) {
          GLOAD_LDS16(Ab + (long)row * 4096 + kt * 64 + gs * 8, sA + hh * 512);
        } else {
          GLOAD_LDS16(Bb + (long)row * 2048 + kt * 64 + gs * 8, sB + hh * 512);
        }
      }
      __syncthreads();

#pragma unroll
      for (int kk = 0; kk < 2; ++kk) {
        short8 af[4], bf2[2];
#pragma unroll
        for (int m = 0; m < 4; ++m) {
          int row = wr * 64 + m * 16 + (lane & 15);
          int g = kk * 4 + (lane >> 4);
          af[m] = *(const short8*)((const char*)sA + row * 128 + ((g ^ (row & 7)) << 4));
        }
#pragma unroll
        for (int n = 0; n < 2; ++n) {
          int row = wc * 32 + n * 16 + (lane & 15);
          int g = kk * 4 + (lane >> 4);
          bf2[n] = *(const short8*)((const char*)sB + row * 128 + ((g ^ (row & 7)) << 4));
        }
#pragma unroll
        for (int m = 0; m < 4; ++m)
#pragma unroll
          for (int n = 0; n < 2; ++n)
            acc[m][n] = __builtin_amdgcn_mfma_f32_16x16x32_bf16(af[m], bf2[n], acc[m][n], 0, 0, 0);
      }
    }

    int r0 = strip * 128 + wr * 64 + (lane >> 4) * 4;
    int c0 = bx * 128 + wc * 32 + (lane & 15);
#pragma unroll
    for (int m = 0; m < 4; ++m)
#pragma unroll
      for (int n = 0; n < 2; ++n)
#pragma unroll
        for (int r = 0; r < 4; ++r)
          Ob[(long)(r0 + m * 16 + r) * 1024 + c0 + n * 16] = acc[m][n][r];
  }
}

// ---------------- causal row softmax, single-read, P bf16 in-place ----------------
__global__ __launch_bounds__(256) void softmax_causal(float* __restrict__ S) {
  int row = blockIdx.x;  // 0..8191
  long b = row >> 11;
  int i = row & 2047;
  float* s = S + (b * 2048 + i) * 2048;
  unsigned short* p = (unsigned short*)s;  // in-place, pitch 4096 ushorts
  int n = i + 1;
  int jEnd = ((i >> 7) + 1) << 7;  // PV reads exactly this far
  int tid = threadIdx.x;
  __shared__ float red[4];

  float vals[8];
  float m = -3.0e38f;
#pragma unroll
  for (int k = 0; k < 8; ++k) {
    int j = tid + k * 256;
    vals[k] = (j < n) ? s[j] : -3.0e38f;
    m = fmaxf(m, vals[k]);
  }
#pragma unroll
  for (int off = 32; off > 0; off >>= 1) m = fmaxf(m, __shfl_xor(m, off));
  if ((tid & 63) == 0) red[tid >> 6] = m;
  __syncthreads();
  m = fmaxf(fmaxf(red[0], red[1]), fmaxf(red[2], red[3]));
  __syncthreads();

  float sum = 0.f;
#pragma unroll
  for (int k = 0; k < 8; ++k) {
    int j = tid + k * 256;
    float e = (j < n) ? __expf(vals[k] - m) : 0.f;
    vals[k] = e;
    sum += e;
  }
#pragma unroll
  for (int off = 32; off > 0; off >>= 1) sum += __shfl_xor(sum, off);
  if ((tid & 63) == 0) red[tid >> 6] = sum;
  __syncthreads();  // also guarantees all s[] reads done before in-place writes
  sum = red[0] + red[1] + red[2] + red[3];
  float inv = 1.0f / sum;

#pragma unroll
  for (int k = 0; k < 8; ++k) {
    int j = tid + k * 256;
    if (j < jEnd) p[j] = f2b(vals[k] * inv);
  }
}

extern "C" void kernel_launch(void* const* d_in, const int* in_sizes, int n_in,
                              void* d_out, int out_size, void* d_ws, size_t ws_size,
                              hipStream_t stream) {
  const float* x = (const float*)d_in[0];
  // d_in[1] = additive causal mask — causality handled analytically
  const float* Wq = (const float*)d_in[2];
  const float* bq = (const float*)d_in[3];
  const float* Wk = (const float*)d_in[4];
  const float* bk = (const float*)d_in[5];
  const float* Wv = (const float*)d_in[6];
  const float* bv = (const float*)d_in[7];
  float* out = (float*)d_out;

  char* ws = (char*)d_ws;
  const long MB = 1 << 20;
  unsigned short* xb = (unsigned short*)(ws);            // 16MB
  unsigned short* Wb = (unsigned short*)(ws + 16 * MB);  // 6MB
  float* biasb = (float*)(ws + 22 * MB);                 // 12KB
  unsigned short* QK = (unsigned short*)(ws + 23 * MB);  // 32MB
  unsigned short* Vt = (unsigned short*)(ws + 55 * MB);  // 16MB
  float* Sbuf = (float*)(ws + 71 * MB);                  // 64MB (P overlaid)

  cvt4<<<8192, 256, 0, stream>>>(x, xb, 2097152);
  prep_w<<<3084, 256, 0, stream>>>(Wq, Wk, Wv, bq, bk, bv, Wb, biasb);

  // fused QKV projection: QK bf16 [8192][2048] + Vt bf16 [4][1024][2048]
  gemm128<0><<<dim3(24, 64, 1), 256, 0, stream>>>(
      xb, Wb, QK, biasb, Vt, 1.0f, 1024, 1024, 2048, 16, 0, 0, 0);

  // scores = (1/32) Q K^T, lower-triangle blocks only, f32
  gemm128<1><<<dim3(16, 16, 4), 256, 0, stream>>>(
      QK, QK + 1024, Sbuf, nullptr, nullptr, 0.03125f, 2048, 2048, 2048, 16,
      2048L * 2048, 2048L * 2048, 2048L * 2048);

  softmax_causal<<<8192, 256, 0, stream>>>(Sbuf);

  // out = P V : pair-balanced causal GEMM
  pv_gemm<<<dim3(8, 8, 4), 512, 0, stream>>>((unsigned short*)Sbuf, Vt, out);
}

// Round 3
// 285.311 us; speedup vs baseline: 1.0567x; 1.0567x over previous
//
#include <hip/hip_runtime.h>
#include <hip/hip_bf16.h>

// B=4, S=2048, D=1024 causal attention head, f32 in/out, bf16 MFMA compute.
//
// ws layout (bytes):
//   [0,16MB)    xb    bf16 [8192][1024]
//   [16,22MB)   Wb    bf16 [3072][1024]   (Wq;Wk;Wv stacked, B^T layout)
//   [22,23MB)   biasb f32  [3072]
//   [23,71MB)   QKV   bf16 [8192][3072]   (cols 0:1024=Q, 1024:2048=K, 2048:3072=V)
//   [71,87MB)   Vt    bf16 [4][1024][2048]
//   [87,151MB)  S     f32  [4][2048][2048]; P bf16 overlaid in-place (row pitch 4096 ushorts)

typedef __attribute__((ext_vector_type(8))) short short8;
typedef __attribute__((ext_vector_type(4))) float f32x4;
typedef __attribute__((ext_vector_type(4))) unsigned short ushort4v;

static __device__ __forceinline__ unsigned short f2b(float f) {
  union { __hip_bfloat16 h; unsigned short u; } cv;
  cv.h = __float2bfloat16(f);
  return cv.u;
}

#define GLOAD_LDS16(gsrc, ldst)                                              \
  __builtin_amdgcn_global_load_lds(                                          \
      (const __attribute__((address_space(1))) void*)(gsrc),                 \
      (__attribute__((address_space(3))) void*)(ldst), 16, 0, 0)

// ---------------- conversions ----------------
__global__ __launch_bounds__(256) void cvt4(const float* __restrict__ in,
                                            unsigned short* __restrict__ out, int n4) {
  int i = blockIdx.x * blockDim.x + threadIdx.x;
  if (i >= n4) return;
  float4 v = reinterpret_cast<const float4*>(in)[i];
  ushort4v o;
  o.x = f2b(v.x); o.y = f2b(v.y); o.z = f2b(v.z); o.w = f2b(v.w);
  reinterpret_cast<ushort4v*>(out)[i] = o;
}

// W cvt (3 matrices) + bias concat in one launch. grid = 3072 + 12.
__global__ __launch_bounds__(256) void prep_w(
    const float* __restrict__ Wq, const float* __restrict__ Wk, const float* __restrict__ Wv,
    const float* __restrict__ bq, const float* __restrict__ bk, const float* __restrict__ bv,
    unsigned short* __restrict__ Wb, float* __restrict__ biasb) {
  int id = blockIdx.x;
  if (id < 3072) {
    int sel = id >> 10;
    const float* src = sel == 0 ? Wq : sel == 1 ? Wk : Wv;
    int i = (id & 1023) * 256 + threadIdx.x;  // float4 index, < 262144
    float4 v = reinterpret_cast<const float4*>(src)[i];
    ushort4v o;
    o.x = f2b(v.x); o.y = f2b(v.y); o.z = f2b(v.z); o.w = f2b(v.w);
    reinterpret_cast<ushort4v*>(Wb + (long)sel * 1048576)[i] = o;
  } else {
    int i = (id - 3072) * 256 + threadIdx.x;  // 0..3071
    if (i < 3072) {
      int sel = i >> 10;
      const float* src = sel == 0 ? bq : sel == 1 ? bk : bv;
      biasb[i] = src[i & 1023];
    }
  }
}

// ---------------- shared GEMM body: 128x128 tile, BK=64, 4 waves (2x2) ----------------
// acc += A_tile * B_tile^T over nkt k-tiles. LDS XOR-swizzle (pre-swizzled global src).
template <typename EPI>
static __device__ __forceinline__ void gemm128_body(
    const unsigned short* __restrict__ Ab, const unsigned short* __restrict__ Bb,
    int lda, int ldb, int nkt, unsigned short* sA, unsigned short* sB, EPI epi) {
  int tid = threadIdx.x;
  int lane = tid & 63;
  int w = tid >> 6;
  int wr = w >> 1, wc = w & 1;

  f32x4 acc[4][4];
#pragma unroll
  for (int m = 0; m < 4; ++m)
#pragma unroll
    for (int n = 0; n < 4; ++n) acc[m][n] = (f32x4){0.f, 0.f, 0.f, 0.f};

  for (int kt = 0; kt < nkt; ++kt) {
    __syncthreads();
#pragma unroll
    for (int c = 0; c < 8; ++c) {
      int chunk = w * 8 + c;
      int half = chunk & 15;
      int L = half * 1024 + lane * 16;
      int row = L >> 7;
      int gs = ((L >> 4) & 7) ^ (row & 7);
      if (chunk < 16) {
        GLOAD_LDS16(Ab + (long)row * lda + kt * 64 + gs * 8, sA + half * 512);
      } else {
        GLOAD_LDS16(Bb + (long)row * ldb + kt * 64 + gs * 8, sB + half * 512);
      }
    }
    __syncthreads();

#pragma unroll
    for (int kk = 0; kk < 2; ++kk) {
      short8 af[4], bfr[4];
#pragma unroll
      for (int m = 0; m < 4; ++m) {
        int row = wr * 64 + m * 16 + (lane & 15);
        int g = kk * 4 + (lane >> 4);
        af[m] = *(const short8*)((const char*)sA + row * 128 + ((g ^ (row & 7)) << 4));
      }
#pragma unroll
      for (int n = 0; n < 4; ++n) {
        int row = wc * 64 + n * 16 + (lane & 15);
        int g = kk * 4 + (lane >> 4);
        bfr[n] = *(const short8*)((const char*)sB + row * 128 + ((g ^ (row & 7)) << 4));
      }
#pragma unroll
      for (int m = 0; m < 4; ++m)
#pragma unroll
        for (int n = 0; n < 4; ++n)
          acc[m][n] = __builtin_amdgcn_mfma_f32_16x16x32_bf16(af[m], bfr[n], acc[m][n], 0, 0, 0);
    }
  }
  // C/D layout: col = lane&15, row = (lane>>4)*4 + reg
  int rloc = wr * 64 + (lane >> 4) * 4;
  int cloc = wc * 64 + (lane & 15);
  epi(acc, rloc, cloc);
}

// ---------------- projection: QKV = xb * Wb^T + bias, bf16 out ----------------
__global__ __launch_bounds__(256) void proj_gemm(
    const unsigned short* __restrict__ A, const unsigned short* __restrict__ B,
    unsigned short* __restrict__ C, const float* __restrict__ bias) {
  __shared__ unsigned short sA[128 * 64];
  __shared__ unsigned short sB[128 * 64];
  int bx = blockIdx.x, by = blockIdx.y;
  const unsigned short* Ab = A + (long)by * 128 * 1024;
  const unsigned short* Bb = B + (long)bx * 128 * 1024;
  gemm128_body(Ab, Bb, 1024, 1024, 16, sA, sB,
               [&](f32x4 acc[4][4], int rloc, int cloc) {
                 int r0 = by * 128 + rloc;
                 int c0 = bx * 128 + cloc;
#pragma unroll
                 for (int m = 0; m < 4; ++m)
#pragma unroll
                   for (int n = 0; n < 4; ++n) {
                     int gc = c0 + n * 16;
                     float bv = bias[gc];
#pragma unroll
                     for (int r = 0; r < 4; ++r)
                       C[(long)(r0 + m * 16 + r) * 3072 + gc] = f2b(acc[m][n][r] + bv);
                   }
               });
}

// ---------------- scores: S = (1/32) Q K^T, packed lower-triangle grid ----------------
__global__ __launch_bounds__(256) void scores_gemm(
    const unsigned short* __restrict__ QKV, float* __restrict__ S) {
  __shared__ unsigned short sA[128 * 64];
  __shared__ unsigned short sB[128 * 64];
  int t = blockIdx.x;  // 0..135 packed (by,bx), bx<=by
  int by = (int)((sqrtf(8.f * t + 1.f) - 1.f) * 0.5f);
  while ((by + 1) * (by + 2) / 2 <= t) ++by;
  while (by * (by + 1) / 2 > t) --by;
  int bx = t - by * (by + 1) / 2;
  long bz = blockIdx.z;
  const unsigned short* Q = QKV + bz * (2048L * 3072);
  const unsigned short* Ab = Q + (long)by * 128 * 3072;
  const unsigned short* Bb = Q + 1024 + (long)bx * 128 * 3072;
  float* Sb = S + bz * (2048L * 2048);
  gemm128_body(Ab, Bb, 3072, 3072, 16, sA, sB,
               [&](f32x4 acc[4][4], int rloc, int cloc) {
                 int r0 = by * 128 + rloc;
                 int c0 = bx * 128 + cloc;
#pragma unroll
                 for (int m = 0; m < 4; ++m)
#pragma unroll
                   for (int n = 0; n < 4; ++n)
#pragma unroll
                     for (int r = 0; r < 4; ++r)
                       Sb[(long)(r0 + m * 16 + r) * 2048 + c0 + n * 16] =
                           acc[m][n][r] * 0.03125f;
               });
}

// ---------------- V transpose: Vt[b][d][s] = V[b][s][d] ----------------
__global__ __launch_bounds__(256) void transpose64(const unsigned short* __restrict__ V,
                                                   unsigned short* __restrict__ Vt) {
  __shared__ unsigned short t[64][72];  // +8 pad breaks bank alignment
  int s0 = blockIdx.x * 64, d0 = blockIdx.y * 64;
  long bz = blockIdx.z;
  const unsigned short* src = V + bz * (2048L * 3072);
  unsigned short* dst = Vt + bz * (1024L * 2048);
  int tid = threadIdx.x;
#pragma unroll
  for (int pp = 0; pp < 2; ++pp) {
    int r = pp * 32 + (tid >> 3);
    int c = (tid & 7) * 8;
    short8 v = *(const short8*)(src + (long)(s0 + r) * 3072 + d0 + c);
    *(short8*)&t[r][c] = v;
  }
  __syncthreads();
#pragma unroll
  for (int pp = 0; pp < 2; ++pp) {
    int d = pp * 32 + (tid >> 3);
    int sc = (tid & 7) * 8;
    short8 v;
#pragma unroll
    for (int k = 0; k < 8; ++k) v[k] = (short)t[sc + k][d];
    *(short8*)(dst + (long)(d0 + d) * 2048 + s0 + sc) = v;
  }
}

// ---------------- causal row softmax, single-read, P bf16 in-place ----------------
__global__ __launch_bounds__(256) void softmax_causal(float* __restrict__ S) {
  int row = blockIdx.x;  // 0..8191
  long b = row >> 11;
  int i = row & 2047;
  float* s = S + (b * 2048 + i) * 2048;
  unsigned short* p = (unsigned short*)s;  // in-place, pitch 4096 ushorts
  int n = i + 1;
  int jEnd = ((i >> 7) + 1) << 7;  // PV reads exactly this far
  int tid = threadIdx.x;
  __shared__ float red[4];

  float vals[8];
  float m = -3.0e38f;
#pragma unroll
  for (int k = 0; k < 8; ++k) {
    int j = tid + k * 256;
    vals[k] = (j < n) ? s[j] : -3.0e38f;
    m = fmaxf(m, vals[k]);
  }
#pragma unroll
  for (int off = 32; off > 0; off >>= 1) m = fmaxf(m, __shfl_xor(m, off));
  if ((tid & 63) == 0) red[tid >> 6] = m;
  __syncthreads();
  m = fmaxf(fmaxf(red[0], red[1]), fmaxf(red[2], red[3]));
  __syncthreads();

  float sum = 0.f;
#pragma unroll
  for (int k = 0; k < 8; ++k) {
    int j = tid + k * 256;
    float e = (j < n) ? __expf(vals[k] - m) : 0.f;
    vals[k] = e;
    sum += e;
  }
#pragma unroll
  for (int off = 32; off > 0; off >>= 1) sum += __shfl_xor(sum, off);
  if ((tid & 63) == 0) red[tid >> 6] = sum;
  __syncthreads();  // all s[] reads done before in-place writes
  sum = red[0] + red[1] + red[2] + red[3];
  float inv = 1.0f / sum;

#pragma unroll
  for (int k = 0; k < 8; ++k) {
    int j = tid + k * 256;
    if (j < jEnd) p[j] = f2b(vals[k] * inv);
  }
}

// ---------------- PV: out[b] = P[b] * Vt[b]^T, pair-balanced causal ----------------
// grid (8,8,4) x 512 thr. Block handles strips {15-byp, byp}: constant 34 ktiles.
__global__ __launch_bounds__(512) void pv_gemm(
    const unsigned short* __restrict__ P, const unsigned short* __restrict__ Vt,
    float* __restrict__ out) {
  __shared__ unsigned short sA[128 * 64];
  __shared__ unsigned short sB[128 * 64];
  int tid = threadIdx.x;
  int lane = tid & 63;
  int w = tid >> 6;  // 0..7
  int wr = w >> 2, wc = w & 3;
  int bx = blockIdx.x, byp = blockIdx.y, bz = blockIdx.z;
  const unsigned short* Pb = P + bz * (2048L * 4096);
  const unsigned short* Bb = Vt + bz * (1024L * 2048) + (long)bx * 128 * 2048;
  float* Ob = out + bz * (2048L * 1024);

#pragma unroll
  for (int half = 0; half < 2; ++half) {
    int strip = half == 0 ? (15 - byp) : byp;
    int nkt = (strip + 1) * 2;
    const unsigned short* Ab = Pb + (long)strip * 128 * 4096;

    f32x4 acc[4][2];
#pragma unroll
    for (int m = 0; m < 4; ++m)
#pragma unroll
      for (int n = 0; n < 2; ++n) acc[m][n] = (f32x4){0.f, 0.f, 0.f, 0.f};

    for (int kt = 0; kt < nkt; ++kt) {
      __syncthreads();
#pragma unroll
      for (int c = 0; c < 4; ++c) {
        int chunk = w * 4 + c;
        int hh = chunk & 15;
        int L = hh * 1024 + lane * 16;
        int row = L >> 7;
        int gs = ((L >> 4) & 7) ^ (row & 7);
        if (chunk < 16) {
          GLOAD_LDS16(Ab + (long)row * 4096 + kt * 64 + gs * 8, sA + hh * 512);
        } else {
          GLOAD_LDS16(Bb + (long)row * 2048 + kt * 64 + gs * 8, sB + hh * 512);
        }
      }
      __syncthreads();

#pragma unroll
      for (int kk = 0; kk < 2; ++kk) {
        short8 af[4], bf2[2];
#pragma unroll
        for (int m = 0; m < 4; ++m) {
          int row = wr * 64 + m * 16 + (lane & 15);
          int g = kk * 4 + (lane >> 4);
          af[m] = *(const short8*)((const char*)sA + row * 128 + ((g ^ (row & 7)) << 4));
        }
#pragma unroll
        for (int n = 0; n < 2; ++n) {
          int row = wc * 32 + n * 16 + (lane & 15);
          int g = kk * 4 + (lane >> 4);
          bf2[n] = *(const short8*)((const char*)sB + row * 128 + ((g ^ (row & 7)) << 4));
        }
#pragma unroll
        for (int m = 0; m < 4; ++m)
#pragma unroll
          for (int n = 0; n < 2; ++n)
            acc[m][n] = __builtin_amdgcn_mfma_f32_16x16x32_bf16(af[m], bf2[n], acc[m][n], 0, 0, 0);
      }
    }

    int r0 = strip * 128 + wr * 64 + (lane >> 4) * 4;
    int c0 = bx * 128 + wc * 32 + (lane & 15);
#pragma unroll
    for (int m = 0; m < 4; ++m)
#pragma unroll
      for (int n = 0; n < 2; ++n)
#pragma unroll
        for (int r = 0; r < 4; ++r)
          Ob[(long)(r0 + m * 16 + r) * 1024 + c0 + n * 16] = acc[m][n][r];
  }
}

extern "C" void kernel_launch(void* const* d_in, const int* in_sizes, int n_in,
                              void* d_out, int out_size, void* d_ws, size_t ws_size,
                              hipStream_t stream) {
  const float* x = (const float*)d_in[0];
  // d_in[1] = additive causal mask — causality handled analytically
  const float* Wq = (const float*)d_in[2];
  const float* bq = (const float*)d_in[3];
  const float* Wk = (const float*)d_in[4];
  const float* bk = (const float*)d_in[5];
  const float* Wv = (const float*)d_in[6];
  const float* bv = (const float*)d_in[7];
  float* out = (float*)d_out;

  char* ws = (char*)d_ws;
  const long MB = 1 << 20;
  unsigned short* xb = (unsigned short*)(ws);            // 16MB
  unsigned short* Wb = (unsigned short*)(ws + 16 * MB);  // 6MB
  float* biasb = (float*)(ws + 22 * MB);                 // 12KB
  unsigned short* QKV = (unsigned short*)(ws + 23 * MB); // 48MB
  unsigned short* Vt = (unsigned short*)(ws + 71 * MB);  // 16MB
  float* Sbuf = (float*)(ws + 87 * MB);                  // 64MB (P overlaid)

  cvt4<<<8192, 256, 0, stream>>>(x, xb, 2097152);
  prep_w<<<3084, 256, 0, stream>>>(Wq, Wk, Wv, bq, bk, bv, Wb, biasb);

  // fused QKV projection: [8192x1024] x [3072x1024]^T -> bf16 [8192x3072]
  proj_gemm<<<dim3(24, 64), 256, 0, stream>>>(xb, Wb, QKV, biasb);

  // Vt[b][d][s]
  transpose64<<<dim3(32, 16, 4), 256, 0, stream>>>(QKV + 2048, Vt);

  // scores = (1/32) Q K^T, packed lower-triangle grid
  scores_gemm<<<dim3(136, 1, 4), 256, 0, stream>>>(QKV, Sbuf);

  // causal softmax, P bf16 in-place (row pitch 4096 ushorts)
  softmax_causal<<<8192, 256, 0, stream>>>(Sbuf);

  // out = P V : pair-balanced causal GEMM
  pv_gemm<<<dim3(8, 8, 4), 512, 0, stream>>>((unsigned short*)Sbuf, Vt, out);
}

// Round 4
// 271.732 us; speedup vs baseline: 1.1095x; 1.0500x over previous
//
#include <hip/hip_runtime.h>
#include <hip/hip_bf16.h>

// B=4, S=2048, D=1024 causal attention head, f32 in/out, bf16 MFMA compute.
//
// ws layout (bytes):
//   [0,16MB)    xb    bf16 [8192][1024]
//   [16,22MB)   Wb    bf16 [3072][1024]   (Wq;Wk;Wv stacked, B^T layout)
//   [22,23MB)   biasb f32  [3072]
//   [23,71MB)   QKV   bf16 [8192][3072]   (cols 0:1024=Q, 1024:2048=K, 2048:3072=V)
//   [71,87MB)   Vt    bf16 [4][1024][2048]
//   [87,151MB)  S     f32  [4][2048][2048]; P bf16 overlaid in-place (row pitch 4096 ushorts)

typedef __attribute__((ext_vector_type(8))) short short8;
typedef __attribute__((ext_vector_type(4))) float f32x4;
typedef __attribute__((ext_vector_type(4))) unsigned short ushort4v;

static __device__ __forceinline__ unsigned short f2b(float f) {
  union { __hip_bfloat16 h; unsigned short u; } cv;
  cv.h = __float2bfloat16(f);
  return cv.u;
}

#define GLOAD_LDS16(gsrc, ldst)                                              \
  __builtin_amdgcn_global_load_lds(                                          \
      (const __attribute__((address_space(1))) void*)(gsrc),                 \
      (__attribute__((address_space(3))) void*)(ldst), 16, 0, 0)

#define WAIT_VM0() asm volatile("s_waitcnt vmcnt(0)" ::: "memory")

// ---------------- conversions ----------------
__global__ __launch_bounds__(256) void cvt4(const float* __restrict__ in,
                                            unsigned short* __restrict__ out, int n4) {
  int i = blockIdx.x * blockDim.x + threadIdx.x;
  if (i >= n4) return;
  float4 v = reinterpret_cast<const float4*>(in)[i];
  ushort4v o;
  o.x = f2b(v.x); o.y = f2b(v.y); o.z = f2b(v.z); o.w = f2b(v.w);
  reinterpret_cast<ushort4v*>(out)[i] = o;
}

// W cvt (3 matrices) + bias concat in one launch. grid = 3072 + 12.
__global__ __launch_bounds__(256) void prep_w(
    const float* __restrict__ Wq, const float* __restrict__ Wk, const float* __restrict__ Wv,
    const float* __restrict__ bq, const float* __restrict__ bk, const float* __restrict__ bv,
    unsigned short* __restrict__ Wb, float* __restrict__ biasb) {
  int id = blockIdx.x;
  if (id < 3072) {
    int sel = id >> 10;
    const float* src = sel == 0 ? Wq : sel == 1 ? Wk : Wv;
    int i = (id & 1023) * 256 + threadIdx.x;
    float4 v = reinterpret_cast<const float4*>(src)[i];
    ushort4v o;
    o.x = f2b(v.x); o.y = f2b(v.y); o.z = f2b(v.z); o.w = f2b(v.w);
    reinterpret_cast<ushort4v*>(Wb + (long)sel * 1048576)[i] = o;
  } else {
    int i = (id - 3072) * 256 + threadIdx.x;
    if (i < 3072) {
      int sel = i >> 10;
      const float* src = sel == 0 ? bq : sel == 1 ? bk : bv;
      biasb[i] = src[i & 1023];
    }
  }
}

// ---------------- projection (round-1 verbatim structure, 62.4us known-good) ----------------
// 128x128 tile, BK=64, 4 waves (2x2). Single-buffered LDS, XOR-swizzle.
__global__ __launch_bounds__(256) void proj_gemm(
    const unsigned short* __restrict__ A, const unsigned short* __restrict__ B,
    unsigned short* __restrict__ Cout, const float* __restrict__ bias,
    int lda, int ldb, int ldc, int ktiles) {
  int bx = blockIdx.x, by = blockIdx.y;

  __shared__ unsigned short sA[128 * 64];
  __shared__ unsigned short sB[128 * 64];

  int tid = threadIdx.x;
  int lane = tid & 63;
  int w = tid >> 6;
  int wr = w >> 1, wc = w & 1;

  const unsigned short* Ab = A + (long)by * 128 * lda;
  const unsigned short* Bb = B + (long)bx * 128 * ldb;

  f32x4 acc[4][4];
#pragma unroll
  for (int m = 0; m < 4; ++m)
#pragma unroll
    for (int n = 0; n < 4; ++n) acc[m][n] = (f32x4){0.f, 0.f, 0.f, 0.f};

  for (int kt = 0; kt < ktiles; ++kt) {
    __syncthreads();
#pragma unroll
    for (int c = 0; c < 8; ++c) {
      int chunk = w * 8 + c;
      int half = chunk & 15;
      int L = half * 1024 + lane * 16;
      int row = L >> 7;
      int gs = ((L >> 4) & 7) ^ (row & 7);
      if (chunk < 16) {
        GLOAD_LDS16(Ab + (long)row * lda + kt * 64 + gs * 8, sA + half * 512);
      } else {
        GLOAD_LDS16(Bb + (long)row * ldb + kt * 64 + gs * 8, sB + half * 512);
      }
    }
    __syncthreads();

#pragma unroll
    for (int kk = 0; kk < 2; ++kk) {
      short8 af[4], bfr[4];
#pragma unroll
      for (int m = 0; m < 4; ++m) {
        int row = wr * 64 + m * 16 + (lane & 15);
        int g = kk * 4 + (lane >> 4);
        af[m] = *(const short8*)((const char*)sA + row * 128 + ((g ^ (row & 7)) << 4));
      }
#pragma unroll
      for (int n = 0; n < 4; ++n) {
        int row = wc * 64 + n * 16 + (lane & 15);
        int g = kk * 4 + (lane >> 4);
        bfr[n] = *(const short8*)((const char*)sB + row * 128 + ((g ^ (row & 7)) << 4));
      }
#pragma unroll
      for (int m = 0; m < 4; ++m)
#pragma unroll
        for (int n = 0; n < 4; ++n)
          acc[m][n] = __builtin_amdgcn_mfma_f32_16x16x32_bf16(af[m], bfr[n], acc[m][n], 0, 0, 0);
    }
  }

  int r0 = by * 128 + wr * 64 + (lane >> 4) * 4;
  int c0 = bx * 128 + wc * 64 + (lane & 15);
#pragma unroll
  for (int m = 0; m < 4; ++m)
#pragma unroll
    for (int n = 0; n < 4; ++n) {
      int gc = c0 + n * 16;
      float bv = bias[gc];
#pragma unroll
      for (int r = 0; r < 4; ++r)
        Cout[(long)(r0 + m * 16 + r) * ldc + gc] = f2b(acc[m][n][r] + bv);
    }
}

// ---------------- scores: S = (1/32) Q K^T, packed triangle, 2-phase dbuf ----------------
__global__ __launch_bounds__(256) void scores_gemm(
    const unsigned short* __restrict__ QKV, float* __restrict__ S) {
  __shared__ unsigned short sA[2][128 * 64];
  __shared__ unsigned short sB[2][128 * 64];
  int t = blockIdx.x;  // 0..135 packed (by,bx), bx<=by
  int by = (int)((sqrtf(8.f * t + 1.f) - 1.f) * 0.5f);
  while ((by + 1) * (by + 2) / 2 <= t) ++by;
  while (by * (by + 1) / 2 > t) --by;
  int bx = t - by * (by + 1) / 2;
  long bz = blockIdx.z;
  const unsigned short* Q = QKV + bz * (2048L * 3072);
  const unsigned short* Ab = Q + (long)by * 128 * 3072;
  const unsigned short* Bb = Q + 1024 + (long)bx * 128 * 3072;

  int tid = threadIdx.x;
  int lane = tid & 63;
  int w = tid >> 6;
  int wr = w >> 1, wc = w & 1;

  f32x4 acc[4][4];
#pragma unroll
  for (int m = 0; m < 4; ++m)
#pragma unroll
    for (int n = 0; n < 4; ++n) acc[m][n] = (f32x4){0.f, 0.f, 0.f, 0.f};

#define SC_STAGE(BUF, KT)                                                        \
  do {                                                                           \
    _Pragma("unroll") for (int c = 0; c < 8; ++c) {                              \
      int chunk = w * 8 + c;                                                     \
      int half = chunk & 15;                                                     \
      int L = half * 1024 + lane * 16;                                           \
      int row = L >> 7;                                                          \
      int gs = ((L >> 4) & 7) ^ (row & 7);                                       \
      if (chunk < 16) {                                                          \
        GLOAD_LDS16(Ab + (long)row * 3072 + (KT) * 64 + gs * 8,                  \
                    &sA[BUF][half * 512]);                                       \
      } else {                                                                   \
        GLOAD_LDS16(Bb + (long)row * 3072 + (KT) * 64 + gs * 8,                  \
                    &sB[BUF][half * 512]);                                       \
      }                                                                          \
    }                                                                            \
  } while (0)

#define SC_COMPUTE(BUF)                                                          \
  do {                                                                           \
    _Pragma("unroll") for (int kk = 0; kk < 2; ++kk) {                           \
      short8 af[4], bfr[4];                                                      \
      _Pragma("unroll") for (int m = 0; m < 4; ++m) {                            \
        int row = wr * 64 + m * 16 + (lane & 15);                                \
        int g = kk * 4 + (lane >> 4);                                            \
        af[m] = *(const short8*)((const char*)sA[BUF] + row * 128 +              \
                                 ((g ^ (row & 7)) << 4));                        \
      }                                                                          \
      _Pragma("unroll") for (int n = 0; n < 4; ++n) {                            \
        int row = wc * 64 + n * 16 + (lane & 15);                                \
        int g = kk * 4 + (lane >> 4);                                            \
        bfr[n] = *(const short8*)((const char*)sB[BUF] + row * 128 +             \
                                  ((g ^ (row & 7)) << 4));                       \
      }                                                                          \
      _Pragma("unroll") for (int m = 0; m < 4; ++m)                              \
          _Pragma("unroll") for (int n = 0; n < 4; ++n) acc[m][n] =              \
          __builtin_amdgcn_mfma_f32_16x16x32_bf16(af[m], bfr[n], acc[m][n],      \
                                                  0, 0, 0);                      \
    }                                                                            \
  } while (0)

  SC_STAGE(0, 0);
  WAIT_VM0();
  __builtin_amdgcn_s_barrier();
#pragma unroll 1
  for (int kt = 0; kt < 16; kt += 2) {
    if (kt + 1 < 16) SC_STAGE(1, kt + 1);
    SC_COMPUTE(0);
    WAIT_VM0();
    __builtin_amdgcn_s_barrier();
    if (kt + 2 < 16) SC_STAGE(0, kt + 2);
    SC_COMPUTE(1);
    WAIT_VM0();
    __builtin_amdgcn_s_barrier();
  }

  float* Sb = S + bz * (2048L * 2048);
  int r0 = by * 128 + wr * 64 + (lane >> 4) * 4;
  int c0 = bx * 128 + wc * 64 + (lane & 15);
#pragma unroll
  for (int m = 0; m < 4; ++m)
#pragma unroll
    for (int n = 0; n < 4; ++n)
#pragma unroll
      for (int r = 0; r < 4; ++r)
        Sb[(long)(r0 + m * 16 + r) * 2048 + c0 + n * 16] = acc[m][n][r] * 0.03125f;
#undef SC_STAGE
#undef SC_COMPUTE
}

// ---------------- V transpose: Vt[b][d][s] = V[b][s][d] ----------------
__global__ __launch_bounds__(256) void transpose64(const unsigned short* __restrict__ V,
                                                   unsigned short* __restrict__ Vt) {
  __shared__ unsigned short t[64][72];
  int s0 = blockIdx.x * 64, d0 = blockIdx.y * 64;
  long bz = blockIdx.z;
  const unsigned short* src = V + bz * (2048L * 3072);
  unsigned short* dst = Vt + bz * (1024L * 2048);
  int tid = threadIdx.x;
#pragma unroll
  for (int pp = 0; pp < 2; ++pp) {
    int r = pp * 32 + (tid >> 3);
    int c = (tid & 7) * 8;
    short8 v = *(const short8*)(src + (long)(s0 + r) * 3072 + d0 + c);
    *(short8*)&t[r][c] = v;
  }
  __syncthreads();
#pragma unroll
  for (int pp = 0; pp < 2; ++pp) {
    int d = pp * 32 + (tid >> 3);
    int sc = (tid & 7) * 8;
    short8 v;
#pragma unroll
    for (int k = 0; k < 8; ++k) v[k] = (short)t[sc + k][d];
    *(short8*)(dst + (long)(d0 + d) * 2048 + s0 + sc) = v;
  }
}

// ---------------- causal row softmax, single-read, P bf16 in-place ----------------
__global__ __launch_bounds__(256) void softmax_causal(float* __restrict__ S) {
  int row = blockIdx.x;
  long b = row >> 11;
  int i = row & 2047;
  float* s = S + (b * 2048 + i) * 2048;
  unsigned short* p = (unsigned short*)s;
  int n = i + 1;
  int jEnd = ((i >> 7) + 1) << 7;
  int tid = threadIdx.x;
  __shared__ float red[4];

  float vals[8];
  float m = -3.0e38f;
#pragma unroll
  for (int k = 0; k < 8; ++k) {
    int j = tid + k * 256;
    vals[k] = (j < n) ? s[j] : -3.0e38f;
    m = fmaxf(m, vals[k]);
  }
#pragma unroll
  for (int off = 32; off > 0; off >>= 1) m = fmaxf(m, __shfl_xor(m, off));
  if ((tid & 63) == 0) red[tid >> 6] = m;
  __syncthreads();
  m = fmaxf(fmaxf(red[0], red[1]), fmaxf(red[2], red[3]));
  __syncthreads();

  float sum = 0.f;
#pragma unroll
  for (int k = 0; k < 8; ++k) {
    int j = tid + k * 256;
    float e = (j < n) ? __expf(vals[k] - m) : 0.f;
    vals[k] = e;
    sum += e;
  }
#pragma unroll
  for (int off = 32; off > 0; off >>= 1) sum += __shfl_xor(sum, off);
  if ((tid & 63) == 0) red[tid >> 6] = sum;
  __syncthreads();
  sum = red[0] + red[1] + red[2] + red[3];
  float inv = 1.0f / sum;

#pragma unroll
  for (int k = 0; k < 8; ++k) {
    int j = tid + k * 256;
    if (j < jEnd) p[j] = f2b(vals[k] * inv);
  }
}

// ---------------- PV: out = P * Vt^T, pair-balanced causal, 2-phase dbuf ----------------
// grid (8,8,4) x 512 thr. Block handles strips {15-byp, byp}: constant 34 ktiles.
__global__ __launch_bounds__(512) void pv_gemm(
    const unsigned short* __restrict__ P, const unsigned short* __restrict__ Vt,
    float* __restrict__ out) {
  __shared__ unsigned short sA[2][128 * 64];
  __shared__ unsigned short sB[2][128 * 64];
  int tid = threadIdx.x;
  int lane = tid & 63;
  int w = tid >> 6;  // 0..7
  int wr = w >> 2, wc = w & 3;
  int bx = blockIdx.x, byp = blockIdx.y, bz = blockIdx.z;
  const unsigned short* Pb = P + bz * (2048L * 4096);
  const unsigned short* Bb = Vt + bz * (1024L * 2048) + (long)bx * 128 * 2048;
  float* Ob = out + bz * (2048L * 1024);

#define PV_STAGE(BUF, KT)                                                        \
  do {                                                                           \
    _Pragma("unroll") for (int c = 0; c < 4; ++c) {                              \
      int chunk = w * 4 + c;                                                     \
      int hh = chunk & 15;                                                       \
      int L = hh * 1024 + lane * 16;                                             \
      int row = L >> 7;                                                          \
      int gs = ((L >> 4) & 7) ^ (row & 7);                                       \
      if (chunk < 16) {                                                          \
        GLOAD_LDS16(Ab + (long)row * 4096 + (KT) * 64 + gs * 8,                  \
                    &sA[BUF][hh * 512]);                                         \
      } else {                                                                   \
        GLOAD_LDS16(Bb + (long)row * 2048 + (KT) * 64 + gs * 8,                  \
                    &sB[BUF][hh * 512]);                                         \
      }                                                                          \
    }                                                                            \
  } while (0)

#define PV_COMPUTE(BUF)                                                          \
  do {                                                                           \
    _Pragma("unroll") for (int kk = 0; kk < 2; ++kk) {                           \
      short8 af[4], bf2[2];                                                      \
      _Pragma("unroll") for (int m = 0; m < 4; ++m) {                            \
        int row = wr * 64 + m * 16 + (lane & 15);                                \
        int g = kk * 4 + (lane >> 4);                                            \
        af[m] = *(const short8*)((const char*)sA[BUF] + row * 128 +              \
                                 ((g ^ (row & 7)) << 4));                        \
      }                                                                          \
      _Pragma("unroll") for (int n = 0; n < 2; ++n) {                            \
        int row = wc * 32 + n * 16 + (lane & 15);                                \
        int g = kk * 4 + (lane >> 4);                                            \
        bf2[n] = *(const short8*)((const char*)sB[BUF] + row * 128 +             \
                                  ((g ^ (row & 7)) << 4));                       \
      }                                                                          \
      _Pragma("unroll") for (int m = 0; m < 4; ++m)                              \
          _Pragma("unroll") for (int n = 0; n < 2; ++n) acc[m][n] =              \
          __builtin_amdgcn_mfma_f32_16x16x32_bf16(af[m], bf2[n], acc[m][n],      \
                                                  0, 0, 0);                      \
    }                                                                            \
  } while (0)

#pragma unroll 1
  for (int half = 0; half < 2; ++half) {
    int strip = half == 0 ? (15 - byp) : byp;
    int nkt = (strip + 1) * 2;  // even
    const unsigned short* Ab = Pb + (long)strip * 128 * 4096;

    f32x4 acc[4][2];
#pragma unroll
    for (int m = 0; m < 4; ++m)
#pragma unroll
      for (int n = 0; n < 2; ++n) acc[m][n] = (f32x4){0.f, 0.f, 0.f, 0.f};

    PV_STAGE(0, 0);
    WAIT_VM0();
    __builtin_amdgcn_s_barrier();
#pragma unroll 1
    for (int kt = 0; kt < nkt; kt += 2) {
      PV_STAGE(1, kt + 1);  // kt+1 < nkt always (nkt even)
      PV_COMPUTE(0);
      WAIT_VM0();
      __builtin_amdgcn_s_barrier();
      if (kt + 2 < nkt) PV_STAGE(0, kt + 2);
      PV_COMPUTE(1);
      WAIT_VM0();
      __builtin_amdgcn_s_barrier();
    }

    int r0 = strip * 128 + wr * 64 + (lane >> 4) * 4;
    int c0 = bx * 128 + wc * 32 + (lane & 15);
#pragma unroll
    for (int m = 0; m < 4; ++m)
#pragma unroll
      for (int n = 0; n < 2; ++n)
#pragma unroll
        for (int r = 0; r < 4; ++r)
          Ob[(long)(r0 + m * 16 + r) * 1024 + c0 + n * 16] = acc[m][n][r];
  }
#undef PV_STAGE
#undef PV_COMPUTE
}

extern "C" void kernel_launch(void* const* d_in, const int* in_sizes, int n_in,
                              void* d_out, int out_size, void* d_ws, size_t ws_size,
                              hipStream_t stream) {
  const float* x = (const float*)d_in[0];
  // d_in[1] = additive causal mask — causality handled analytically
  const float* Wq = (const float*)d_in[2];
  const float* bq = (const float*)d_in[3];
  const float* Wk = (const float*)d_in[4];
  const float* bk = (const float*)d_in[5];
  const float* Wv = (const float*)d_in[6];
  const float* bv = (const float*)d_in[7];
  float* out = (float*)d_out;

  char* ws = (char*)d_ws;
  const long MB = 1 << 20;
  unsigned short* xb = (unsigned short*)(ws);            // 16MB
  unsigned short* Wb = (unsigned short*)(ws + 16 * MB);  // 6MB
  float* biasb = (float*)(ws + 22 * MB);                 // 12KB
  unsigned short* QKV = (unsigned short*)(ws + 23 * MB); // 48MB
  unsigned short* Vt = (unsigned short*)(ws + 71 * MB);  // 16MB
  float* Sbuf = (float*)(ws + 87 * MB);                  // 64MB (P overlaid)

  cvt4<<<8192, 256, 0, stream>>>(x, xb, 2097152);
  prep_w<<<3084, 256, 0, stream>>>(Wq, Wk, Wv, bq, bk, bv, Wb, biasb);

  // fused QKV projection: [8192x1024] x [3072x1024]^T -> bf16 [8192x3072]
  proj_gemm<<<dim3(24, 64), 256, 0, stream>>>(xb, Wb, QKV, biasb, 1024, 1024, 3072, 16);

  // Vt[b][d][s]
  transpose64<<<dim3(32, 16, 4), 256, 0, stream>>>(QKV + 2048, Vt);

  // scores = (1/32) Q K^T, packed lower-triangle grid, 2-phase dbuf
  scores_gemm<<<dim3(136, 1, 4), 256, 0, stream>>>(QKV, Sbuf);

  // causal softmax, P bf16 in-place (row pitch 4096 ushorts)
  softmax_causal<<<8192, 256, 0, stream>>>(Sbuf);

  // out = P V : pair-balanced causal GEMM, 2-phase dbuf
  pv_gemm<<<dim3(8, 8, 4), 512, 0, stream>>>((unsigned short*)Sbuf, Vt, out);
}

// Round 7
// 267.252 us; speedup vs baseline: 1.1281x; 1.0168x over previous
//
#include <hip/hip_runtime.h>
#include <hip/hip_bf16.h>

// B=4, S=2048, D=1024 causal attention head, f32 in/out, bf16 MFMA compute.
// Round-4-proven structure + XCD-paired grids + 1-wave softmax (only deltas).
//
// ws layout (bytes):
//   [0,16MB)    xb    bf16 [8192][1024]
//   [16,22MB)   Wb    bf16 [3072][1024]   (Wq;Wk;Wv stacked, B^T layout)
//   [22,23MB)   biasb f32  [3072]
//   [23,71MB)   QKV   bf16 [8192][3072]   (cols 0:1024=Q, 1024:2048=K, 2048:3072=V)
//   [71,87MB)   Vt    bf16 [4][1024][2048]
//   [87,151MB)  S     f32  [4][2048][2048]; P bf16 overlaid in-place (row pitch 4096 ushorts)

typedef __attribute__((ext_vector_type(8))) short short8;
typedef __attribute__((ext_vector_type(4))) float f32x4;
typedef __attribute__((ext_vector_type(4))) unsigned short ushort4v;

static __device__ __forceinline__ unsigned short f2b(float f) {
  union { __hip_bfloat16 h; unsigned short u; } cv;
  cv.h = __float2bfloat16(f);
  return cv.u;
}

#define GLOAD_LDS16(gsrc, ldst)                                              \
  __builtin_amdgcn_global_load_lds(                                          \
      (const __attribute__((address_space(1))) void*)(gsrc),                 \
      (__attribute__((address_space(3))) void*)(ldst), 16, 0, 0)

#define WAIT_VM0() asm volatile("s_waitcnt vmcnt(0)" ::: "memory")

// ---------------- conversions ----------------
__global__ __launch_bounds__(256) void cvt4(const float* __restrict__ in,
                                            unsigned short* __restrict__ out, int n4) {
  int i = blockIdx.x * blockDim.x + threadIdx.x;
  if (i >= n4) return;
  float4 v = reinterpret_cast<const float4*>(in)[i];
  ushort4v o;
  o.x = f2b(v.x); o.y = f2b(v.y); o.z = f2b(v.z); o.w = f2b(v.w);
  reinterpret_cast<ushort4v*>(out)[i] = o;
}

// W cvt (3 matrices) + bias concat in one launch. grid = 3072 + 12.
__global__ __launch_bounds__(256) void prep_w(
    const float* __restrict__ Wq, const float* __restrict__ Wk, const float* __restrict__ Wv,
    const float* __restrict__ bq, const float* __restrict__ bk, const float* __restrict__ bv,
    unsigned short* __restrict__ Wb, float* __restrict__ biasb) {
  int id = blockIdx.x;
  if (id < 3072) {
    int sel = id >> 10;
    const float* src = sel == 0 ? Wq : sel == 1 ? Wk : Wv;
    int i = (id & 1023) * 256 + threadIdx.x;
    float4 v = reinterpret_cast<const float4*>(src)[i];
    ushort4v o;
    o.x = f2b(v.x); o.y = f2b(v.y); o.z = f2b(v.z); o.w = f2b(v.w);
    reinterpret_cast<ushort4v*>(Wb + (long)sel * 1048576)[i] = o;
  } else {
    int i = (id - 3072) * 256 + threadIdx.x;
    if (i < 3072) {
      int sel = i >> 10;
      const float* src = sel == 0 ? bq : sel == 1 ? bk : bv;
      biasb[i] = src[i & 1023];
    }
  }
}

// ---------------- projection (round-1/4 verbatim, 62.4us known-good) ----------------
// 128x128 tile, BK=64, 4 waves (2x2). Single-buffered LDS, XOR-swizzle.
__global__ __launch_bounds__(256) void proj_gemm(
    const unsigned short* __restrict__ A, const unsigned short* __restrict__ B,
    unsigned short* __restrict__ Cout, const float* __restrict__ bias,
    int lda, int ldb, int ldc, int ktiles) {
  int bx = blockIdx.x, by = blockIdx.y;

  __shared__ unsigned short sA[128 * 64];
  __shared__ unsigned short sB[128 * 64];

  int tid = threadIdx.x;
  int lane = tid & 63;
  int w = tid >> 6;
  int wr = w >> 1, wc = w & 1;

  const unsigned short* Ab = A + (long)by * 128 * lda;
  const unsigned short* Bb = B + (long)bx * 128 * ldb;

  f32x4 acc[4][4];
#pragma unroll
  for (int m = 0; m < 4; ++m)
#pragma unroll
    for (int n = 0; n < 4; ++n) acc[m][n] = (f32x4){0.f, 0.f, 0.f, 0.f};

  for (int kt = 0; kt < ktiles; ++kt) {
    __syncthreads();
#pragma unroll
    for (int c = 0; c < 8; ++c) {
      int chunk = w * 8 + c;
      int half = chunk & 15;
      int L = half * 1024 + lane * 16;
      int row = L >> 7;
      int gs = ((L >> 4) & 7) ^ (row & 7);
      if (chunk < 16) {
        GLOAD_LDS16(Ab + (long)row * lda + kt * 64 + gs * 8, sA + half * 512);
      } else {
        GLOAD_LDS16(Bb + (long)row * ldb + kt * 64 + gs * 8, sB + half * 512);
      }
    }
    __syncthreads();

#pragma unroll
    for (int kk = 0; kk < 2; ++kk) {
      short8 af[4], bfr[4];
#pragma unroll
      for (int m = 0; m < 4; ++m) {
        int row = wr * 64 + m * 16 + (lane & 15);
        int g = kk * 4 + (lane >> 4);
        af[m] = *(const short8*)((const char*)sA + row * 128 + ((g ^ (row & 7)) << 4));
      }
#pragma unroll
      for (int n = 0; n < 4; ++n) {
        int row = wc * 64 + n * 16 + (lane & 15);
        int g = kk * 4 + (lane >> 4);
        bfr[n] = *(const short8*)((const char*)sB + row * 128 + ((g ^ (row & 7)) << 4));
      }
#pragma unroll
      for (int m = 0; m < 4; ++m)
#pragma unroll
        for (int n = 0; n < 4; ++n)
          acc[m][n] = __builtin_amdgcn_mfma_f32_16x16x32_bf16(af[m], bfr[n], acc[m][n], 0, 0, 0);
    }
  }

  int r0 = by * 128 + wr * 64 + (lane >> 4) * 4;
  int c0 = bx * 128 + wc * 64 + (lane & 15);
#pragma unroll
  for (int m = 0; m < 4; ++m)
#pragma unroll
    for (int n = 0; n < 4; ++n) {
      int gc = c0 + n * 16;
      float bv = bias[gc];
#pragma unroll
      for (int r = 0; r < 4; ++r)
        Cout[(long)(r0 + m * 16 + r) * ldc + gc] = f2b(acc[m][n][r] + bv);
    }
}

// ---------------- scores: S = (1/32) Q K^T, XCD-paired causal grid, 2-phase dbuf ------
// grid (8,17,4): XCD c8 owns triangle rows {c8, 15-c8} -> 17 blocks each, Q strips
// L2-resident per XCD. Same GEMM body as round-4 (proven).
__global__ __launch_bounds__(256) void scores_gemm(
    const unsigned short* __restrict__ QKV, float* __restrict__ S) {
  __shared__ unsigned short sA[2][128 * 64];
  __shared__ unsigned short sB[2][128 * 64];
  int c8 = blockIdx.x, j = blockIdx.y;  // linear id = c8 + 8*j -> XCD c8
  int by = (j <= c8) ? c8 : 15 - c8;
  int bx = (j <= c8) ? j : j - c8 - 1;  // bx <= by always
  long bz = blockIdx.z;
  const unsigned short* Q = QKV + bz * (2048L * 3072);
  const unsigned short* Ab = Q + (long)by * 128 * 3072;
  const unsigned short* Bb = Q + 1024 + (long)bx * 128 * 3072;

  int tid = threadIdx.x;
  int lane = tid & 63;
  int w = tid >> 6;
  int wr = w >> 1, wc = w & 1;

  f32x4 acc[4][4];
#pragma unroll
  for (int m = 0; m < 4; ++m)
#pragma unroll
    for (int n = 0; n < 4; ++n) acc[m][n] = (f32x4){0.f, 0.f, 0.f, 0.f};

#define SC_STAGE(BUF, KT)                                                        \
  do {                                                                           \
    _Pragma("unroll") for (int c = 0; c < 8; ++c) {                              \
      int chunk = w * 8 + c;                                                     \
      int half = chunk & 15;                                                     \
      int L = half * 1024 + lane * 16;                                           \
      int row = L >> 7;                                                          \
      int gs = ((L >> 4) & 7) ^ (row & 7);                                       \
      if (chunk < 16) {                                                          \
        GLOAD_LDS16(Ab + (long)row * 3072 + (KT) * 64 + gs * 8,                  \
                    &sA[BUF][half * 512]);                                       \
      } else {                                                                   \
        GLOAD_LDS16(Bb + (long)row * 3072 + (KT) * 64 + gs * 8,                  \
                    &sB[BUF][half * 512]);                                       \
      }                                                                          \
    }                                                                            \
  } while (0)

#define SC_COMPUTE(BUF)                                                          \
  do {                                                                           \
    _Pragma("unroll") for (int kk = 0; kk < 2; ++kk) {                           \
      short8 af[4], bfr[4];                                                      \
      _Pragma("unroll") for (int m = 0; m < 4; ++m) {                            \
        int row = wr * 64 + m * 16 + (lane & 15);                                \
        int g = kk * 4 + (lane >> 4);                                            \
        af[m] = *(const short8*)((const char*)sA[BUF] + row * 128 +              \
                                 ((g ^ (row & 7)) << 4));                        \
      }                                                                          \
      _Pragma("unroll") for (int n = 0; n < 4; ++n) {                            \
        int row = wc * 64 + n * 16 + (lane & 15);                                \
        int g = kk * 4 + (lane >> 4);                                            \
        bfr[n] = *(const short8*)((const char*)sB[BUF] + row * 128 +             \
                                  ((g ^ (row & 7)) << 4));                       \
      }                                                                          \
      _Pragma("unroll") for (int m = 0; m < 4; ++m)                              \
          _Pragma("unroll") for (int n = 0; n < 4; ++n) acc[m][n] =              \
          __builtin_amdgcn_mfma_f32_16x16x32_bf16(af[m], bfr[n], acc[m][n],      \
                                                  0, 0, 0);                      \
    }                                                                            \
  } while (0)

  SC_STAGE(0, 0);
  WAIT_VM0();
  __builtin_amdgcn_s_barrier();
#pragma unroll 1
  for (int kt = 0; kt < 16; kt += 2) {
    if (kt + 1 < 16) SC_STAGE(1, kt + 1);
    SC_COMPUTE(0);
    WAIT_VM0();
    __builtin_amdgcn_s_barrier();
    if (kt + 2 < 16) SC_STAGE(0, kt + 2);
    SC_COMPUTE(1);
    WAIT_VM0();
    __builtin_amdgcn_s_barrier();
  }

  float* Sb = S + bz * (2048L * 2048);
  int r0 = by * 128 + wr * 64 + (lane >> 4) * 4;
  int c0 = bx * 128 + wc * 64 + (lane & 15);
#pragma unroll
  for (int m = 0; m < 4; ++m)
#pragma unroll
    for (int n = 0; n < 4; ++n)
#pragma unroll
      for (int r = 0; r < 4; ++r)
        Sb[(long)(r0 + m * 16 + r) * 2048 + c0 + n * 16] = acc[m][n][r] * 0.03125f;
#undef SC_STAGE
#undef SC_COMPUTE
}

// ---------------- V transpose: Vt[b][d][s] = V[b][s][d] (round-4 proven) ----------------
__global__ __launch_bounds__(256) void transpose64(const unsigned short* __restrict__ V,
                                                   unsigned short* __restrict__ Vt) {
  __shared__ unsigned short t[64][72];
  int s0 = blockIdx.x * 64, d0 = blockIdx.y * 64;
  long bz = blockIdx.z;
  const unsigned short* src = V + bz * (2048L * 3072);
  unsigned short* dst = Vt + bz * (1024L * 2048);
  int tid = threadIdx.x;
#pragma unroll
  for (int pp = 0; pp < 2; ++pp) {
    int r = pp * 32 + (tid >> 3);
    int c = (tid & 7) * 8;
    short8 v = *(const short8*)(src + (long)(s0 + r) * 3072 + d0 + c);
    *(short8*)&t[r][c] = v;
  }
  __syncthreads();
#pragma unroll
  for (int pp = 0; pp < 2; ++pp) {
    int d = pp * 32 + (tid >> 3);
    int sc = (tid & 7) * 8;
    short8 v;
#pragma unroll
    for (int k = 0; k < 8; ++k) v[k] = (short)t[sc + k][d];
    *(short8*)(dst + (long)(d0 + d) * 2048 + s0 + sc) = v;
  }
}

// ---------------- causal row softmax: one wave per row, registers only ----------------
__global__ __launch_bounds__(64) void softmax_causal(float* __restrict__ S) {
  int row = blockIdx.x;  // 0..8191
  long b = row >> 11;
  int i = row & 2047;
  float* s = S + (b * 2048 + i) * 2048;
  unsigned short* p = (unsigned short*)s;  // in-place, pitch 4096 ushorts
  int n = i + 1;
  int jEnd = ((i >> 7) + 1) << 7;  // PV reads exactly this far
  int lane = threadIdx.x;

  float vals[32];
  float m = -3.0e38f;
#pragma unroll
  for (int k = 0; k < 32; ++k) {
    int j = lane + k * 64;
    vals[k] = (j < n) ? s[j] : -3.0e38f;
    m = fmaxf(m, vals[k]);
  }
#pragma unroll
  for (int off = 32; off > 0; off >>= 1) m = fmaxf(m, __shfl_xor(m, off));

  float sum = 0.f;
#pragma unroll
  for (int k = 0; k < 32; ++k) {
    int j = lane + k * 64;
    float e = (j < n) ? __expf(vals[k] - m) : 0.f;
    vals[k] = e;
    sum += e;
  }
#pragma unroll
  for (int off = 32; off > 0; off >>= 1) sum += __shfl_xor(sum, off);
  float inv = 1.0f / sum;
  // all reads done (shfl is wave-synchronous) -> safe to overwrite in place
#pragma unroll
  for (int k = 0; k < 32; ++k) {
    int j = lane + k * 64;
    if (j < jEnd) p[j] = f2b(vals[k] * inv);
  }
}

// ---------------- PV: out = P * Vt^T, pair-balanced causal, XCD-local P, dbuf --------
// grid (8,8,4), x = byp -> the 8 bx blocks sharing strips {15-byp,byp} co-locate per XCD.
__global__ __launch_bounds__(512) void pv_gemm(
    const unsigned short* __restrict__ P, const unsigned short* __restrict__ Vt,
    float* __restrict__ out) {
  __shared__ unsigned short sA[2][128 * 64];
  __shared__ unsigned short sB[2][128 * 64];
  int tid = threadIdx.x;
  int lane = tid & 63;
  int w = tid >> 6;  // 0..7
  int wr = w >> 2, wc = w & 3;
  int byp = blockIdx.x, bx = blockIdx.y, bz = blockIdx.z;  // x-major -> XCD = byp
  const unsigned short* Pb = P + bz * (2048L * 4096);
  const unsigned short* Bb = Vt + bz * (1024L * 2048) + (long)bx * 128 * 2048;
  float* Ob = out + bz * (2048L * 1024);

#define PV_STAGE(BUF, KT)                                                        \
  do {                                                                           \
    _Pragma("unroll") for (int c = 0; c < 4; ++c) {                              \
      int chunk = w * 4 + c;                                                     \
      int hh = chunk & 15;                                                       \
      int L = hh * 1024 + lane * 16;                                             \
      int row = L >> 7;                                                          \
      int gs = ((L >> 4) & 7) ^ (row & 7);                                       \
      if (chunk < 16) {                                                          \
        GLOAD_LDS16(Ab + (long)row * 4096 + (KT) * 64 + gs * 8,                  \
                    &sA[BUF][hh * 512]);                                         \
      } else {                                                                   \
        GLOAD_LDS16(Bb + (long)row * 2048 + (KT) * 64 + gs * 8,                  \
                    &sB[BUF][hh * 512]);                                         \
      }                                                                          \
    }                                                                            \
  } while (0)

#define PV_COMPUTE(BUF)                                                          \
  do {                                                                           \
    _Pragma("unroll") for (int kk = 0; kk < 2; ++kk) {                           \
      short8 af[4], bf2[2];                                                      \
      _Pragma("unroll") for (int m = 0; m < 4; ++m) {                            \
        int row = wr * 64 + m * 16 + (lane & 15);                                \
        int g = kk * 4 + (lane >> 4);                                            \
        af[m] = *(const short8*)((const char*)sA[BUF] + row * 128 +              \
                                 ((g ^ (row & 7)) << 4));                        \
      }                                                                          \
      _Pragma("unroll") for (int n = 0; n < 2; ++n) {                            \
        int row = wc * 32 + n * 16 + (lane & 15);                                \
        int g = kk * 4 + (lane >> 4);                                            \
        bf2[n] = *(const short8*)((const char*)sB[BUF] + row * 128 +             \
                                  ((g ^ (row & 7)) << 4));                       \
      }                                                                          \
      _Pragma("unroll") for (int m = 0; m < 4; ++m)                              \
          _Pragma("unroll") for (int n = 0; n < 2; ++n) acc[m][n] =              \
          __builtin_amdgcn_mfma_f32_16x16x32_bf16(af[m], bf2[n], acc[m][n],      \
                                                  0, 0, 0);                      \
    }                                                                            \
  } while (0)

#pragma unroll 1
  for (int half = 0; half < 2; ++half) {
    int strip = half == 0 ? (15 - byp) : byp;
    int nkt = (strip + 1) * 2;  // even
    const unsigned short* Ab = Pb + (long)strip * 128 * 4096;

    f32x4 acc[4][2];
#pragma unroll
    for (int m = 0; m < 4; ++m)
#pragma unroll
      for (int n = 0; n < 2; ++n) acc[m][n] = (f32x4){0.f, 0.f, 0.f, 0.f};

    PV_STAGE(0, 0);
    WAIT_VM0();
    __builtin_amdgcn_s_barrier();
#pragma unroll 1
    for (int kt = 0; kt < nkt; kt += 2) {
      PV_STAGE(1, kt + 1);  // kt+1 < nkt always (nkt even)
      PV_COMPUTE(0);
      WAIT_VM0();
      __builtin_amdgcn_s_barrier();
      if (kt + 2 < nkt) PV_STAGE(0, kt + 2);
      PV_COMPUTE(1);
      WAIT_VM0();
      __builtin_amdgcn_s_barrier();
    }

    int r0 = strip * 128 + wr * 64 + (lane >> 4) * 4;
    int c0 = bx * 128 + wc * 32 + (lane & 15);
#pragma unroll
    for (int m = 0; m < 4; ++m)
#pragma unroll
      for (int n = 0; n < 2; ++n)
#pragma unroll
        for (int r = 0; r < 4; ++r)
          Ob[(long)(r0 + m * 16 + r) * 1024 + c0 + n * 16] = acc[m][n][r];
  }
#undef PV_STAGE
#undef PV_COMPUTE
}

extern "C" void kernel_launch(void* const* d_in, const int* in_sizes, int n_in,
                              void* d_out, int out_size, void* d_ws, size_t ws_size,
                              hipStream_t stream) {
  const float* x = (const float*)d_in[0];
  // d_in[1] = additive causal mask — causality handled analytically
  const float* Wq = (const float*)d_in[2];
  const float* bq = (const float*)d_in[3];
  const float* Wk = (const float*)d_in[4];
  const float* bk = (const float*)d_in[5];
  const float* Wv = (const float*)d_in[6];
  const float* bv = (const float*)d_in[7];
  float* out = (float*)d_out;

  char* ws = (char*)d_ws;
  const long MB = 1 << 20;
  unsigned short* xb = (unsigned short*)(ws);            // 16MB
  unsigned short* Wb = (unsigned short*)(ws + 16 * MB);  // 6MB
  float* biasb = (float*)(ws + 22 * MB);                 // 12KB
  unsigned short* QKV = (unsigned short*)(ws + 23 * MB); // 48MB
  unsigned short* Vt = (unsigned short*)(ws + 71 * MB);  // 16MB
  float* Sbuf = (float*)(ws + 87 * MB);                  // 64MB (P overlaid)

  cvt4<<<8192, 256, 0, stream>>>(x, xb, 2097152);
  prep_w<<<3084, 256, 0, stream>>>(Wq, Wk, Wv, bq, bk, bv, Wb, biasb);

  // fused QKV projection: [8192x1024] x [3072x1024]^T -> bf16 [8192x3072]
  proj_gemm<<<dim3(24, 64), 256, 0, stream>>>(xb, Wb, QKV, biasb, 1024, 1024, 3072, 16);

  // Vt[b][d][s]
  transpose64<<<dim3(32, 16, 4), 256, 0, stream>>>(QKV + 2048, Vt);

  // scores = (1/32) Q K^T, XCD-paired causal grid, 2-phase dbuf
  scores_gemm<<<dim3(8, 17, 4), 256, 0, stream>>>(QKV, Sbuf);

  // causal softmax, P bf16 in-place (row pitch 4096 ushorts)
  softmax_causal<<<8192, 64, 0, stream>>>(Sbuf);

  // out = P V : pair-balanced causal GEMM, XCD-local P strips, 2-phase dbuf
  pv_gemm<<<dim3(8, 8, 4), 512, 0, stream>>>((unsigned short*)Sbuf, Vt, out);
}

// Round 8
// 258.473 us; speedup vs baseline: 1.1664x; 1.0340x over previous
//
#include <hip/hip_runtime.h>
#include <hip/hip_bf16.h>

// B=4, S=2048, D=1024 causal attention head, f32 in/out, bf16 MFMA compute.
// R7-proven GEMM bodies; pipeline consolidated to 5 kernels; S stored bf16.
//
// ws layout (bytes):
//   [0,16MB)    xb    bf16 [8192][1024]
//   [16,22MB)   Wb    bf16 [3072][1024]   (Wq;Wk;Wv stacked, B^T layout)
//   [22,23MB)   biasb f32  [3072]
//   [23,55MB)   QK    bf16 [8192][2048]   (cols 0:1024=Q, 1024:2048=K)
//   [55,71MB)   Vt    bf16 [4][1024][2048]  (written by proj epilogue, LDS-transposed)
//   [71,103MB)  S     bf16 [4][2048][2048]; P bf16 in-place after softmax

typedef __attribute__((ext_vector_type(8))) short short8;
typedef __attribute__((ext_vector_type(4))) float f32x4;
typedef __attribute__((ext_vector_type(4))) unsigned short ushort4v;
typedef __attribute__((ext_vector_type(2))) unsigned short ushort2v;

static __device__ __forceinline__ unsigned short f2b(float f) {
  union { __hip_bfloat16 h; unsigned short u; } cv;
  cv.h = __float2bfloat16(f);
  return cv.u;
}
static __device__ __forceinline__ float b2f(unsigned short u) {
  union { unsigned int i; float f; } cv;
  cv.i = ((unsigned int)u) << 16;
  return cv.f;
}

#define GLOAD_LDS16(gsrc, ldst)                                              \
  __builtin_amdgcn_global_load_lds(                                          \
      (const __attribute__((address_space(1))) void*)(gsrc),                 \
      (__attribute__((address_space(3))) void*)(ldst), 16, 0, 0)

#define WAIT_VM0() asm volatile("s_waitcnt vmcnt(0)" ::: "memory")

// ---------------- prep: x cvt + W cvt + bias concat, one launch ----------------
// grid = 8192 (x) + 3072 (W) + 12 (bias) = 11276 blocks x 256.
__global__ __launch_bounds__(256) void prep(
    const float* __restrict__ x,
    const float* __restrict__ Wq, const float* __restrict__ Wk, const float* __restrict__ Wv,
    const float* __restrict__ bq, const float* __restrict__ bk, const float* __restrict__ bv,
    unsigned short* __restrict__ xb, unsigned short* __restrict__ Wb,
    float* __restrict__ biasb) {
  int id = blockIdx.x;
  if (id < 8192) {
    int i = id * 256 + threadIdx.x;  // < 2097152 exactly
    float4 v = reinterpret_cast<const float4*>(x)[i];
    ushort4v o;
    o.x = f2b(v.x); o.y = f2b(v.y); o.z = f2b(v.z); o.w = f2b(v.w);
    reinterpret_cast<ushort4v*>(xb)[i] = o;
  } else if (id < 11264) {
    int id2 = id - 8192;
    int sel = id2 >> 10;
    const float* src = sel == 0 ? Wq : sel == 1 ? Wk : Wv;
    int i = (id2 & 1023) * 256 + threadIdx.x;  // < 262144
    float4 v = reinterpret_cast<const float4*>(src)[i];
    ushort4v o;
    o.x = f2b(v.x); o.y = f2b(v.y); o.z = f2b(v.z); o.w = f2b(v.w);
    reinterpret_cast<ushort4v*>(Wb + (long)sel * 1048576)[i] = o;
  } else {
    int i = (id - 11264) * 256 + threadIdx.x;  // < 3072 exactly
    if (i < 3072) {
      int sel = i >> 10;
      const float* src = sel == 0 ? bq : sel == 1 ? bk : bv;
      biasb[i] = src[i & 1023];
    }
  }
}

// ---------------- projection (62us-proven loop) + fused V transpose ----------------
// 128x128 tile, BK=64, 4 waves (2x2). Single-buffered LDS, XOR-swizzle.
// bx<16 -> QK bf16 (pitch 2048) + bias; bx>=16 -> Vt[b][d][s] via 2-phase LDS
// transpose (T[64][132] = 16896B fits the 32KB sbuf).
__global__ __launch_bounds__(256) void proj_gemm(
    const unsigned short* __restrict__ A, const unsigned short* __restrict__ B,
    unsigned short* __restrict__ QKout, unsigned short* __restrict__ VtOut,
    const float* __restrict__ bias) {
  int bx = blockIdx.x, by = blockIdx.y;

  __shared__ unsigned short sbuf[2 * 128 * 64];  // sA | sB; epilogue reuses as T[64][132]
  unsigned short* sA = sbuf;
  unsigned short* sB = sbuf + 128 * 64;

  int tid = threadIdx.x;
  int lane = tid & 63;
  int w = tid >> 6;
  int wr = w >> 1, wc = w & 1;

  const unsigned short* Ab = A + (long)by * 128 * 1024;
  const unsigned short* Bb = B + (long)bx * 128 * 1024;

  f32x4 acc[4][4];
#pragma unroll
  for (int m = 0; m < 4; ++m)
#pragma unroll
    for (int n = 0; n < 4; ++n) acc[m][n] = (f32x4){0.f, 0.f, 0.f, 0.f};

  for (int kt = 0; kt < 16; ++kt) {
    __syncthreads();
#pragma unroll
    for (int c = 0; c < 8; ++c) {
      int chunk = w * 8 + c;
      int half = chunk & 15;
      int L = half * 1024 + lane * 16;
      int row = L >> 7;
      int gs = ((L >> 4) & 7) ^ (row & 7);
      if (chunk < 16) {
        GLOAD_LDS16(Ab + (long)row * 1024 + kt * 64 + gs * 8, sA + half * 512);
      } else {
        GLOAD_LDS16(Bb + (long)row * 1024 + kt * 64 + gs * 8, sB + half * 512);
      }
    }
    __syncthreads();

#pragma unroll
    for (int kk = 0; kk < 2; ++kk) {
      short8 af[4], bfr[4];
#pragma unroll
      for (int m = 0; m < 4; ++m) {
        int row = wr * 64 + m * 16 + (lane & 15);
        int g = kk * 4 + (lane >> 4);
        af[m] = *(const short8*)((const char*)sA + row * 128 + ((g ^ (row & 7)) << 4));
      }
#pragma unroll
      for (int n = 0; n < 4; ++n) {
        int row = wc * 64 + n * 16 + (lane & 15);
        int g = kk * 4 + (lane >> 4);
        bfr[n] = *(const short8*)((const char*)sB + row * 128 + ((g ^ (row & 7)) << 4));
      }
#pragma unroll
      for (int m = 0; m < 4; ++m)
#pragma unroll
        for (int n = 0; n < 4; ++n)
          acc[m][n] = __builtin_amdgcn_mfma_f32_16x16x32_bf16(af[m], bfr[n], acc[m][n], 0, 0, 0);
    }
  }

  // C/D layout: col = lane&15, row = (lane>>4)*4 + reg
  if (bx < 16) {
    int r0 = by * 128 + wr * 64 + (lane >> 4) * 4;
    int c0 = bx * 128 + wc * 64 + (lane & 15);
#pragma unroll
    for (int m = 0; m < 4; ++m)
#pragma unroll
      for (int n = 0; n < 4; ++n) {
        int gc = c0 + n * 16;
        float bv = bias[gc];
#pragma unroll
        for (int r = 0; r < 4; ++r)
          QKout[(long)(r0 + m * 16 + r) * 2048 + gc] = f2b(acc[m][n][r] + bv);
      }
  } else {
    // V tile: 2-phase transpose through LDS. Phase h: waves with wc==h deposit
    // their 64 d-cols into T[64][132]; all 256 threads copy the half out coalesced.
    __syncthreads();  // all waves done with sbuf staging reads
    unsigned short(*T)[132] = (unsigned short(*)[132])sbuf;  // 16896B <= 32KB
    int sl0 = wr * 64 + (lane >> 4) * 4;
    int d0 = (bx - 16) * 128;
    long b = by >> 4;
    int s0 = (by & 15) * 128;
    unsigned short* VT = VtOut + b * (1024L * 2048) + (long)d0 * 2048 + s0;
#pragma unroll
    for (int h = 0; h < 2; ++h) {
      if (wc == h) {
#pragma unroll
        for (int m = 0; m < 4; ++m)
#pragma unroll
          for (int n = 0; n < 4; ++n) {
            int dloc = (lane & 15) + n * 16;  // 0..63 within this half
            float bv = bias[2048 + d0 + h * 64 + dloc];
            ushort4v o;
            o.x = f2b(acc[m][n][0] + bv);
            o.y = f2b(acc[m][n][1] + bv);
            o.z = f2b(acc[m][n][2] + bv);
            o.w = f2b(acc[m][n][3] + bv);
            *(ushort4v*)&T[dloc][sl0 + m * 16] = o;  // 8B-aligned (264*dl + 8k)
          }
      }
      __syncthreads();
      // copy 64 rows x 128 cols: 8 passes, 8 rows/pass, 32 lanes x 4 elems per row
#pragma unroll
      for (int pass = 0; pass < 8; ++pass) {
        int d = pass * 8 + (tid >> 5);
        int c = (tid & 31) * 4;
        ushort4v v = *(const ushort4v*)&T[d][c];
        *(ushort4v*)(VT + (long)(h * 64 + d) * 2048 + c) = v;
      }
      __syncthreads();  // before next phase overwrites T
    }
  }
}

// ---------------- scores: S = (1/32) Q K^T bf16, XCD-paired causal grid, dbuf ------
// grid (8,17,4): XCD c8 owns triangle rows {c8, 15-c8} -> 17 blocks each.
__global__ __launch_bounds__(256) void scores_gemm(
    const unsigned short* __restrict__ QK, unsigned short* __restrict__ S) {
  __shared__ unsigned short sA[2][128 * 64];
  __shared__ unsigned short sB[2][128 * 64];
  int c8 = blockIdx.x, j = blockIdx.y;  // linear id = c8 + 8*j -> XCD c8
  int by = (j <= c8) ? c8 : 15 - c8;
  int bx = (j <= c8) ? j : j - c8 - 1;  // bx <= by always
  long bz = blockIdx.z;
  const unsigned short* Ab = QK + (bz * 2048 + (long)by * 128) * 2048;
  const unsigned short* Bb = QK + (bz * 2048 + (long)bx * 128) * 2048 + 1024;

  int tid = threadIdx.x;
  int lane = tid & 63;
  int w = tid >> 6;
  int wr = w >> 1, wc = w & 1;

  f32x4 acc[4][4];
#pragma unroll
  for (int m = 0; m < 4; ++m)
#pragma unroll
    for (int n = 0; n < 4; ++n) acc[m][n] = (f32x4){0.f, 0.f, 0.f, 0.f};

#define SC_STAGE(BUF, KT)                                                        \
  do {                                                                           \
    _Pragma("unroll") for (int c = 0; c < 8; ++c) {                              \
      int chunk = w * 8 + c;                                                     \
      int half = chunk & 15;                                                     \
      int L = half * 1024 + lane * 16;                                           \
      int row = L >> 7;                                                          \
      int gs = ((L >> 4) & 7) ^ (row & 7);                                       \
      if (chunk < 16) {                                                          \
        GLOAD_LDS16(Ab + (long)row * 2048 + (KT) * 64 + gs * 8,                  \
                    &sA[BUF][half * 512]);                                       \
      } else {                                                                   \
        GLOAD_LDS16(Bb + (long)row * 2048 + (KT) * 64 + gs * 8,                  \
                    &sB[BUF][half * 512]);                                       \
      }                                                                          \
    }                                                                            \
  } while (0)

#define SC_COMPUTE(BUF)                                                          \
  do {                                                                           \
    _Pragma("unroll") for (int kk = 0; kk < 2; ++kk) {                           \
      short8 af[4], bfr[4];                                                      \
      _Pragma("unroll") for (int m = 0; m < 4; ++m) {                            \
        int row = wr * 64 + m * 16 + (lane & 15);                                \
        int g = kk * 4 + (lane >> 4);                                            \
        af[m] = *(const short8*)((const char*)sA[BUF] + row * 128 +              \
                                 ((g ^ (row & 7)) << 4));                        \
      }                                                                          \
      _Pragma("unroll") for (int n = 0; n < 4; ++n) {                            \
        int row = wc * 64 + n * 16 + (lane & 15);                                \
        int g = kk * 4 + (lane >> 4);                                            \
        bfr[n] = *(const short8*)((const char*)sB[BUF] + row * 128 +             \
                                  ((g ^ (row & 7)) << 4));                       \
      }                                                                          \
      _Pragma("unroll") for (int m = 0; m < 4; ++m)                              \
          _Pragma("unroll") for (int n = 0; n < 4; ++n) acc[m][n] =              \
          __builtin_amdgcn_mfma_f32_16x16x32_bf16(af[m], bfr[n], acc[m][n],      \
                                                  0, 0, 0);                      \
    }                                                                            \
  } while (0)

  SC_STAGE(0, 0);
  WAIT_VM0();
  __builtin_amdgcn_s_barrier();
#pragma unroll 1
  for (int kt = 0; kt < 16; kt += 2) {
    if (kt + 1 < 16) SC_STAGE(1, kt + 1);
    SC_COMPUTE(0);
    WAIT_VM0();
    __builtin_amdgcn_s_barrier();
    if (kt + 2 < 16) SC_STAGE(0, kt + 2);
    SC_COMPUTE(1);
    WAIT_VM0();
    __builtin_amdgcn_s_barrier();
  }

  unsigned short* Sb = S + bz * (2048L * 2048);
  int r0 = by * 128 + wr * 64 + (lane >> 4) * 4;
  int c0 = bx * 128 + wc * 64 + (lane & 15);
#pragma unroll
  for (int m = 0; m < 4; ++m)
#pragma unroll
    for (int n = 0; n < 4; ++n)
#pragma unroll
      for (int r = 0; r < 4; ++r)
        Sb[(long)(r0 + m * 16 + r) * 2048 + c0 + n * 16] = f2b(acc[m][n][r] * 0.03125f);
#undef SC_STAGE
#undef SC_COMPUTE
}

// ---------------- causal row softmax: one wave per row, bf16 in/out, in-place ----------
__global__ __launch_bounds__(64) void softmax_causal(unsigned short* __restrict__ S) {
  int row = blockIdx.x;  // 0..8191
  long b = row >> 11;
  int i = row & 2047;
  unsigned short* s = S + (b * 2048 + i) * 2048;
  int n = i + 1;
  int jEnd = ((i >> 7) + 1) << 7;  // PV reads exactly this far
  int lane = threadIdx.x;

  float vals[32];
  float m = -3.0e38f;
#pragma unroll
  for (int k = 0; k < 16; ++k) {
    int j0 = lane * 2 + k * 128;
    ushort2v v = *(const ushort2v*)(s + j0);
    float a = (j0 < n) ? b2f(v.x) : -3.0e38f;
    float bb = (j0 + 1 < n) ? b2f(v.y) : -3.0e38f;
    vals[2 * k] = a;
    vals[2 * k + 1] = bb;
    m = fmaxf(m, fmaxf(a, bb));
  }
#pragma unroll
  for (int off = 32; off > 0; off >>= 1) m = fmaxf(m, __shfl_xor(m, off));

  float sum = 0.f;
#pragma unroll
  for (int k = 0; k < 32; ++k) {
    int j = (lane * 2) + (k >> 1) * 128 + (k & 1);
    float e = (j < n) ? __expf(vals[k] - m) : 0.f;
    vals[k] = e;
    sum += e;
  }
#pragma unroll
  for (int off = 32; off > 0; off >>= 1) sum += __shfl_xor(sum, off);
  float inv = 1.0f / sum;
  // all reads done (wave-synchronous) -> safe to overwrite in place
#pragma unroll
  for (int k = 0; k < 16; ++k) {
    int j0 = lane * 2 + k * 128;
    if (j0 < jEnd) {
      ushort2v o;
      o.x = f2b(vals[2 * k] * inv);
      o.y = f2b(vals[2 * k + 1] * inv);
      *(ushort2v*)(s + j0) = o;
    }
  }
}

// ---------------- PV: out = P * Vt^T, pair-balanced causal, XCD-local P, dbuf --------
// grid (8,8,4), x = byp -> the 8 bx blocks sharing strips {15-byp,byp} per XCD.
// P pitch now 2048 ushorts (bf16 S buffer).
__global__ __launch_bounds__(512) void pv_gemm(
    const unsigned short* __restrict__ P, const unsigned short* __restrict__ Vt,
    float* __restrict__ out) {
  __shared__ unsigned short sA[2][128 * 64];
  __shared__ unsigned short sB[2][128 * 64];
  int tid = threadIdx.x;
  int lane = tid & 63;
  int w = tid >> 6;  // 0..7
  int wr = w >> 2, wc = w & 3;
  int byp = blockIdx.x, bx = blockIdx.y, bz = blockIdx.z;  // x-major -> XCD = byp
  const unsigned short* Pb = P + bz * (2048L * 2048);
  const unsigned short* Bb = Vt + bz * (1024L * 2048) + (long)bx * 128 * 2048;
  float* Ob = out + bz * (2048L * 1024);

#define PV_STAGE(BUF, KT)                                                        \
  do {                                                                           \
    _Pragma("unroll") for (int c = 0; c < 4; ++c) {                              \
      int chunk = w * 4 + c;                                                     \
      int hh = chunk & 15;                                                       \
      int L = hh * 1024 + lane * 16;                                             \
      int row = L >> 7;                                                          \
      int gs = ((L >> 4) & 7) ^ (row & 7);                                       \
      if (chunk < 16) {                                                          \
        GLOAD_LDS16(Ab + (long)row * 2048 + (KT) * 64 + gs * 8,                  \
                    &sA[BUF][hh * 512]);                                         \
      } else {                                                                   \
        GLOAD_LDS16(Bb + (long)row * 2048 + (KT) * 64 + gs * 8,                  \
                    &sB[BUF][hh * 512]);                                         \
      }                                                                          \
    }                                                                            \
  } while (0)

#define PV_COMPUTE(BUF)                                                          \
  do {                                                                           \
    _Pragma("unroll") for (int kk = 0; kk < 2; ++kk) {                           \
      short8 af[4], bf2[2];                                                      \
      _Pragma("unroll") for (int m = 0; m < 4; ++m) {                            \
        int row = wr * 64 + m * 16 + (lane & 15);                                \
        int g = kk * 4 + (lane >> 4);                                            \
        af[m] = *(const short8*)((const char*)sA[BUF] + row * 128 +              \
                                 ((g ^ (row & 7)) << 4));                        \
      }                                                                          \
      _Pragma("unroll") for (int n = 0; n < 2; ++n) {                            \
        int row = wc * 32 + n * 16 + (lane & 15);                                \
        int g = kk * 4 + (lane >> 4);                                            \
        bf2[n] = *(const short8*)((const char*)sB[BUF] + row * 128 +             \
                                  ((g ^ (row & 7)) << 4));                       \
      }                                                                          \
      _Pragma("unroll") for (int m = 0; m < 4; ++m)                              \
          _Pragma("unroll") for (int n = 0; n < 2; ++n) acc[m][n] =              \
          __builtin_amdgcn_mfma_f32_16x16x32_bf16(af[m], bf2[n], acc[m][n],      \
                                                  0, 0, 0);                      \
    }                                                                            \
  } while (0)

#pragma unroll 1
  for (int half = 0; half < 2; ++half) {
    int strip = half == 0 ? (15 - byp) : byp;
    int nkt = (strip + 1) * 2;  // even
    const unsigned short* Ab = Pb + (long)strip * 128 * 2048;

    f32x4 acc[4][2];
#pragma unroll
    for (int m = 0; m < 4; ++m)
#pragma unroll
      for (int n = 0; n < 2; ++n) acc[m][n] = (f32x4){0.f, 0.f, 0.f, 0.f};

    PV_STAGE(0, 0);
    WAIT_VM0();
    __builtin_amdgcn_s_barrier();
#pragma unroll 1
    for (int kt = 0; kt < nkt; kt += 2) {
      PV_STAGE(1, kt + 1);  // kt+1 < nkt always (nkt even)
      PV_COMPUTE(0);
      WAIT_VM0();
      __builtin_amdgcn_s_barrier();
      if (kt + 2 < nkt) PV_STAGE(0, kt + 2);
      PV_COMPUTE(1);
      WAIT_VM0();
      __builtin_amdgcn_s_barrier();
    }

    int r0 = strip * 128 + wr * 64 + (lane >> 4) * 4;
    int c0 = bx * 128 + wc * 32 + (lane & 15);
#pragma unroll
    for (int m = 0; m < 4; ++m)
#pragma unroll
      for (int n = 0; n < 2; ++n)
#pragma unroll
        for (int r = 0; r < 4; ++r)
          Ob[(long)(r0 + m * 16 + r) * 1024 + c0 + n * 16] = acc[m][n][r];
  }
#undef PV_STAGE
#undef PV_COMPUTE
}

extern "C" void kernel_launch(void* const* d_in, const int* in_sizes, int n_in,
                              void* d_out, int out_size, void* d_ws, size_t ws_size,
                              hipStream_t stream) {
  const float* x = (const float*)d_in[0];
  // d_in[1] = additive causal mask — causality handled analytically
  const float* Wq = (const float*)d_in[2];
  const float* bq = (const float*)d_in[3];
  const float* Wk = (const float*)d_in[4];
  const float* bk = (const float*)d_in[5];
  const float* Wv = (const float*)d_in[6];
  const float* bv = (const float*)d_in[7];
  float* out = (float*)d_out;

  char* ws = (char*)d_ws;
  const long MB = 1 << 20;
  unsigned short* xb = (unsigned short*)(ws);            // 16MB
  unsigned short* Wb = (unsigned short*)(ws + 16 * MB);  // 6MB
  float* biasb = (float*)(ws + 22 * MB);                 // 12KB
  unsigned short* QK = (unsigned short*)(ws + 23 * MB);  // 32MB
  unsigned short* Vt = (unsigned short*)(ws + 55 * MB);  // 16MB
  unsigned short* Sbuf = (unsigned short*)(ws + 71 * MB);// 32MB bf16 (P in-place)

  // all conversions in one launch
  prep<<<11276, 256, 0, stream>>>(x, Wq, Wk, Wv, bq, bk, bv, xb, Wb, biasb);

  // fused QKV projection: QK bf16 [8192][2048] + Vt bf16 [4][1024][2048]
  proj_gemm<<<dim3(24, 64), 256, 0, stream>>>(xb, Wb, QK, Vt, biasb);

  // scores = (1/32) Q K^T -> bf16, XCD-paired causal grid, 2-phase dbuf
  scores_gemm<<<dim3(8, 17, 4), 256, 0, stream>>>(QK, Sbuf);

  // causal softmax, bf16 in/out, in-place
  softmax_causal<<<8192, 64, 0, stream>>>(Sbuf);

  // out = P V : pair-balanced causal GEMM, XCD-local P strips, 2-phase dbuf
  pv_gemm<<<dim3(8, 8, 4), 512, 0, stream>>>(Sbuf, Vt, out);
}